// Round 8
// baseline (400.955 us; speedup 1.0000x reference)
//
#include <hip/hip_runtime.h>
#include <stdint.h>

typedef int int32x4  __attribute__((ext_vector_type(4)));
typedef int int32x16 __attribute__((ext_vector_type(16)));

#define IN_F   4096
#define OUT_F  4096
#define ROWS   8192   /* 4 * 2048 */

#define BM 128
#define BN 128
#define BK 128

// async global->LDS, 16B per lane; LDS side must be lane-contiguous (m104/m108)
#define GLOAD_LDS16(g, l)                                                      \
  __builtin_amdgcn_global_load_lds(                                            \
      (const __attribute__((address_space(1))) void*)(g),                      \
      (__attribute__((address_space(3))) void*)(l), 16, 0, 0)

__device__ __forceinline__ int pack4i(int a, int b, int c, int d) {
  return (a & 0xff) | ((b & 0xff) << 8) | ((c & 0xff) << 16) | (d << 24);
}

// ---- fused conversion: x int32->int8 and w fp32->int8, one launch -----------
#define XB 32768
#define WB 16384
__global__ void __launch_bounds__(256) cvt_kernel(const int4* __restrict__ x,
                                                  const float4* __restrict__ w,
                                                  int* __restrict__ ox,
                                                  int* __restrict__ ow) {
  int b = blockIdx.x;
  if (b < XB) {
    size_t i = (size_t)b * 256 + threadIdx.x;
    int4 a = x[i];
    ox[i] = pack4i(a.x, a.y, a.z, a.w);
  } else {
    size_t i = (size_t)(b - XB) * 256 + threadIdx.x;
    float4 a = w[i];
    ow[i] = pack4i(__float2int_rn(a.x), __float2int_rn(a.y),
                   __float2int_rn(a.z), __float2int_rn(a.w));
  }
}

// ---- i8 MFMA GEMM: C[m,n] = sum_k A[m,k]*B[n,k]  (both row-major [rows][K]) -
// 128x128 tile, BK=128, DOUBLE-BUFFERED LDS (2 stages x 2 matrices x 16 KB =
// 64 KB; R7 bug was 8 KB/matrix -> tile overlap) with ONE barrier/iter:
//   barrier -> issue tile k+1 into buf 1-p -> ds_read+MFMA on buf p.
// The compiler's vmcnt(0)-before-s_barrier then drains loads issued a full
// MFMA phase (~600 CU-cyc) earlier, hiding the ~500-900 cyc global latency
// that the issue->barrier->compute structure exposed every iteration.
// 4 waves in 2x2, each wave 64x64 via 2x2 mfma_i32_32x32x32_i8.
// A-operand: m = lane&31, k = (lane>>5)*16 + j.  C/D: col = lane&31,
// row = (reg&3) + 8*(reg>>2) + 4*(lane>>5)  [m74/m101, dtype-independent].
// LDS XOR-swizzle (applied on GLOBAL src addr during staging): 16B chunk
// (row, kc) stored at slot kc ^ (row&7).
__global__ void __launch_bounds__(256) gemm_i8_kernel(
    const int8_t* __restrict__ A8, const int8_t* __restrict__ B8,
    const float* __restrict__ bias, const float* __restrict__ alpha_p,
    int* __restrict__ out) {
  __shared__ int8_t lds[2][2][BM * BK];  // [stage][A|B][16 KB] = 64 KB

  const int t = threadIdx.x;
  const int wave = t >> 6;
  const int lane = t & 63;
  const int l31 = lane & 31;
  const int hi  = lane >> 5;    // 0..1
  const int wm = wave >> 1;     // 0..1
  const int wn = wave & 1;      // 0..1

  const int bn = blockIdx.x;    // 0..31
  const int bm = blockIdx.y;    // 0..63

  // staging: 1024 chunks of 16B per matrix; thread t owns chunks t+256j,
  // j=0..3 (rows rowS+32j; 32 is mult of 8 -> swizzle bits unchanged).
  const int rowS = t >> 3;                          // 0..31
  const int colS = ((t & 7) ^ (rowS & 7)) * 16;
  const int8_t* ag = A8 + (size_t)(bm * BM + rowS) * IN_F + colS;
  const int8_t* bg = B8 + (size_t)(bn * BN + rowS) * IN_F + colS;

  // fragment read idx (16B units): row*8 + (kc ^ (row&7)),
  // row = wm*64 + mi*32 + l31 -> row&7 == l31&7; kc = ks*2 + hi.
  const int swz = l31 & 7;
  const int arow0 = (wm * 64 + l31) * 8;   // +mi*256
  const int brow0 = (wn * 64 + l31) * 8;   // +ni*256

  int32x16 acc[2][2] = {};

  // prologue: stage tile 0 into p=0
#pragma unroll
  for (int j = 0; j < 4; ++j) {
    GLOAD_LDS16(ag + (size_t)(32 * j) * IN_F, &lds[0][0][t * 16 + 4096 * j]);
    GLOAD_LDS16(bg + (size_t)(32 * j) * IN_F, &lds[0][1][t * 16 + 4096 * j]);
  }

  int p = 0;
  for (int k0 = 0; k0 < IN_F; k0 += BK) {
    __syncthreads();  // drains tile-k loads (issued one MFMA phase ago);
                      // also protects buf 1-p against overwrite-while-read
    const int k1 = k0 + BK;
    if (k1 < IN_F) {  // scalar-uniform: issue next tile into the other buffer
#pragma unroll
      for (int j = 0; j < 4; ++j) {
        GLOAD_LDS16(ag + k1 + (size_t)(32 * j) * IN_F,
                    &lds[1 - p][0][t * 16 + 4096 * j]);
        GLOAD_LDS16(bg + k1 + (size_t)(32 * j) * IN_F,
                    &lds[1 - p][1][t * 16 + 4096 * j]);
      }
    }

    const int32x4* As4 = (const int32x4*)lds[p][0];
    const int32x4* Bs4 = (const int32x4*)lds[p][1];
#pragma unroll
    for (int ks = 0; ks < 4; ++ks) {
      const int ksw = (ks * 2 + hi) ^ swz;
      int32x4 af[2], bf[2];
#pragma unroll
      for (int i = 0; i < 2; ++i) af[i] = As4[arow0 + i * 256 + ksw];
#pragma unroll
      for (int i = 0; i < 2; ++i) bf[i] = Bs4[brow0 + i * 256 + ksw];
#pragma unroll
      for (int mi = 0; mi < 2; ++mi)
#pragma unroll
        for (int ni = 0; ni < 2; ++ni)
          acc[mi][ni] = __builtin_amdgcn_mfma_i32_32x32x32_i8(
              af[mi], bf[ni], acc[mi][ni], 0, 0, 0);
    }
    p ^= 1;
  }

  // epilogue: C/D col = lane&31, row = (reg&3) + 8*(reg>>2) + 4*hi
  const float alpha = *alpha_p;
#pragma unroll
  for (int mi = 0; mi < 2; ++mi) {
    const int rowt = bm * BM + wm * 64 + mi * 32 + hi * 4;
#pragma unroll
    for (int ni = 0; ni < 2; ++ni) {
      const int col = bn * BN + wn * 64 + ni * 32 + l31;
      const float bv = bias[col];
#pragma unroll
      for (int r = 0; r < 16; ++r) {
        const int row = rowt + (r & 3) + 8 * (r >> 2);
        float v = rintf((float)acc[mi][ni][r] * alpha + bv);
        v = fminf(fmaxf(v, -128.f), 127.f);
        out[(size_t)row * OUT_F + col] = (int)v;
      }
    }
  }
}

extern "C" void kernel_launch(void* const* d_in, const int* in_sizes, int n_in,
                              void* d_out, int out_size, void* d_ws, size_t ws_size,
                              hipStream_t stream) {
  const int*   x     = (const int*)d_in[0];    // [8192, 4096] int8-valued
  const float* w     = (const float*)d_in[1];  // [4096, 4096] int8-valued
  const float* bias  = (const float*)d_in[2];  // [4096]
  const float* alpha = (const float*)d_in[3];  // scalar
  int* out = (int*)d_out;                      // [8192, 4096] int32 (int8 values)

  int8_t* x8 = (int8_t*)d_ws;                        // 33,554,432 B
  int8_t* w8 = x8 + (size_t)ROWS * IN_F;             // 16,777,216 B (total 48 MB)

  cvt_kernel<<<XB + WB, 256, 0, stream>>>((const int4*)x, (const float4*)w,
                                          (int*)x8, (int*)w8);

  dim3 grid(OUT_F / BN, ROWS / BM);  // (32, 64)
  gemm_i8_kernel<<<grid, 256, 0, stream>>>(x8, w8, bias, alpha, out);
}

// Round 9
// 398.056 us; speedup vs baseline: 1.0073x; 1.0073x over previous
//
#include <hip/hip_runtime.h>
#include <stdint.h>

typedef int int32x4  __attribute__((ext_vector_type(4)));
typedef int int32x16 __attribute__((ext_vector_type(16)));

#define IN_F   4096
#define OUT_F  4096
#define ROWS   8192   /* 4 * 2048 */

#define BM 256
#define BN 128
#define BK 128

// async global->LDS, 16B per lane; LDS side must be lane-contiguous (m104/m108)
#define GLOAD_LDS16(g, l)                                                      \
  __builtin_amdgcn_global_load_lds(                                            \
      (const __attribute__((address_space(1))) void*)(g),                      \
      (__attribute__((address_space(3))) void*)(l), 16, 0, 0)

__device__ __forceinline__ int pack4i(int a, int b, int c, int d) {
  return (a & 0xff) | ((b & 0xff) << 8) | ((c & 0xff) << 16) | (d << 24);
}

// ---- fused conversion: x int32->int8 and w fp32->int8, one launch -----------
#define XB 32768
#define WB 16384
__global__ void __launch_bounds__(256) cvt_kernel(const int4* __restrict__ x,
                                                  const float4* __restrict__ w,
                                                  int* __restrict__ ox,
                                                  int* __restrict__ ow) {
  int b = blockIdx.x;
  if (b < XB) {
    size_t i = (size_t)b * 256 + threadIdx.x;
    int4 a = x[i];
    ox[i] = pack4i(a.x, a.y, a.z, a.w);
  } else {
    size_t i = (size_t)(b - XB) * 256 + threadIdx.x;
    float4 a = w[i];
    ow[i] = pack4i(__float2int_rn(a.x), __float2int_rn(a.y),
                   __float2int_rn(a.z), __float2int_rn(a.w));
  }
}

// ---- i8 MFMA GEMM: C[m,n] = sum_k A[m,k]*B[n,k]  (both row-major [rows][K]) -
// R8 post-mortem: LDS read pipe is the co-bottleneck (64 ds_read_b128/iter/CU
// x 12cyc = 768 > 586 MFMA cyc).  Fix: raise register-block reuse.
// Block tile 256x128, BK=128, SINGLE-buffer LDS (dbuf measured neutral, R8):
// As 32 KB + Bs 16 KB = 48 KB -> 2 blocks/CU.  4 waves in 2x2 (wm row-half,
// wn col-half); wave tile 128x64 = 4x2 tiles of mfma_i32_32x32x32_i8.
// Per ks-step: 4 A-reads + 2 B-reads -> 8 MFMAs (0.75 reads/MFMA vs 1.0).
// A-operand: m = lane&31, k = (lane>>5)*16 + j.  C/D: col = lane&31,
// row = (reg&3) + 8*(reg>>2) + 4*(lane>>5)  [m74/m101, dtype-independent].
// LDS XOR-swizzle (applied on GLOBAL src addr during staging): 16B chunk
// (row, kc) stored at slot kc ^ (row&7).
__global__ void __launch_bounds__(256, 2) gemm_i8_kernel(
    const int8_t* __restrict__ A8, const int8_t* __restrict__ B8,
    const float* __restrict__ bias, const float* __restrict__ alpha_p,
    int* __restrict__ out) {
  __shared__ int8_t As[BM * BK];  // 32 KB
  __shared__ int8_t Bs[BN * BK];  // 16 KB

  const int t = threadIdx.x;
  const int wave = t >> 6;
  const int lane = t & 63;
  const int l31 = lane & 31;
  const int hi  = lane >> 5;    // 0..1
  const int wm = wave >> 1;     // 0..1  row half (128 rows)
  const int wn = wave & 1;      // 0..1  col half (64 cols)

  const int bn = blockIdx.x;    // 0..31
  const int bm = blockIdx.y;    // 0..31

  // staging: A 2048 chunks of 16B (8/thread), B 1024 chunks (4/thread);
  // thread t owns chunks t+256j (rows rowS+32j; 32 mult of 8 -> swizzle bits
  // unchanged).
  const int rowS = t >> 3;                          // 0..31
  const int colS = ((t & 7) ^ (rowS & 7)) * 16;
  const int8_t* ag = A8 + (size_t)(bm * BM + rowS) * IN_F + colS;
  const int8_t* bg = B8 + (size_t)(bn * BN + rowS) * IN_F + colS;

  // fragment read idx (16B units): row*8 + (kc ^ (row&7)),
  // row = wm*128 + mi*32 + l31 -> row&7 == l31&7; kc = ks*2 + hi.
  const int swz = l31 & 7;
  const int arow0 = (wm * 128 + l31) * 8;  // +mi*256
  const int brow0 = (wn * 64 + l31) * 8;   // +ni*256

  int32x16 acc[4][2] = {};

  for (int k0 = 0; k0 < IN_F; k0 += BK) {
#pragma unroll
    for (int j = 0; j < 8; ++j)
      GLOAD_LDS16(ag + k0 + (size_t)(32 * j) * IN_F, As + t * 16 + 4096 * j);
#pragma unroll
    for (int j = 0; j < 4; ++j)
      GLOAD_LDS16(bg + k0 + (size_t)(32 * j) * IN_F, Bs + t * 16 + 4096 * j);
    __syncthreads();

    const int32x4* As4 = (const int32x4*)As;
    const int32x4* Bs4 = (const int32x4*)Bs;
#pragma unroll
    for (int ks = 0; ks < 4; ++ks) {
      const int ksw = (ks * 2 + hi) ^ swz;
      int32x4 af[4], bf[2];
#pragma unroll
      for (int i = 0; i < 4; ++i) af[i] = As4[arow0 + i * 256 + ksw];
#pragma unroll
      for (int i = 0; i < 2; ++i) bf[i] = Bs4[brow0 + i * 256 + ksw];
#pragma unroll
      for (int mi = 0; mi < 4; ++mi)
#pragma unroll
        for (int ni = 0; ni < 2; ++ni)
          acc[mi][ni] = __builtin_amdgcn_mfma_i32_32x32x32_i8(
              af[mi], bf[ni], acc[mi][ni], 0, 0, 0);
    }
    __syncthreads();
  }

  // epilogue: C/D col = lane&31, row = (reg&3) + 8*(reg>>2) + 4*hi
  const float alpha = *alpha_p;
#pragma unroll
  for (int mi = 0; mi < 4; ++mi) {
    const int rowt = bm * BM + wm * 128 + mi * 32 + hi * 4;
#pragma unroll
    for (int ni = 0; ni < 2; ++ni) {
      const int col = bn * BN + wn * 64 + ni * 32 + l31;
      const float bv = bias[col];
#pragma unroll
      for (int r = 0; r < 16; ++r) {
        const int row = rowt + (r & 3) + 8 * (r >> 2);
        float v = rintf((float)acc[mi][ni][r] * alpha + bv);
        v = fminf(fmaxf(v, -128.f), 127.f);
        out[(size_t)row * OUT_F + col] = (int)v;
      }
    }
  }
}

extern "C" void kernel_launch(void* const* d_in, const int* in_sizes, int n_in,
                              void* d_out, int out_size, void* d_ws, size_t ws_size,
                              hipStream_t stream) {
  const int*   x     = (const int*)d_in[0];    // [8192, 4096] int8-valued
  const float* w     = (const float*)d_in[1];  // [4096, 4096] int8-valued
  const float* bias  = (const float*)d_in[2];  // [4096]
  const float* alpha = (const float*)d_in[3];  // scalar
  int* out = (int*)d_out;                      // [8192, 4096] int32 (int8 values)

  int8_t* x8 = (int8_t*)d_ws;                        // 33,554,432 B
  int8_t* w8 = x8 + (size_t)ROWS * IN_F;             // 16,777,216 B (total 48 MB)

  cvt_kernel<<<XB + WB, 256, 0, stream>>>((const int4*)x, (const float4*)w,
                                          (int*)x8, (int*)w8);

  dim3 grid(OUT_F / BN, ROWS / BM);  // (32, 32)
  gemm_i8_kernel<<<grid, 256, 0, stream>>>(x8, w8, bias, alpha, out);
}